// Round 15
// baseline (175.023 us; speedup 1.0000x reference)
//
#include <hip/hip_runtime.h>
#include <math.h>

#define BATCH_ 65536
#define NN 512
#define KK 48
#define OFF_HHRE (2*BATCH_*KK)            // 6291456
#define OFF_HHIM (OFF_HHRE + BATCH_*NN)   // 39845888

typedef float f32x4 __attribute__((ext_vector_type(4)));
typedef int   i32x4 __attribute__((ext_vector_type(4)));
typedef short bf16x8 __attribute__((ext_vector_type(8)));

// ---- ws layout (byte offsets) ----
#define WS_FR    0u         // 16 chunks x 16384 B = 262144 B
#define WS_SIGP  262144u    // 256 f32
#define WS_SIGMA 263168u    // 1 f32
#define WS_BPART 264192u    // 4096*2 f32 = 32 KB
#define WS_BVAL  296960u    // 2 f32

__device__ __forceinline__ unsigned short f2bf(float x) {
  unsigned u = __builtin_bit_cast(unsigned, x);
  unsigned r = (u + 0x7fffu + ((u >> 16) & 1u)) >> 16;
  return (unsigned short)r;
}
// single-instruction packed f32->bf16 (RTNE, same as f2bf)
__device__ __forceinline__ int cvtpk(float lo, float hi) {
  int r;
  asm("v_cvt_pk_bf16_f32 %0, %1, %2" : "=v"(r) : "v"(lo), "v"(hi));
  return r;
}
__device__ __forceinline__ i32x4 pack8bf_pk(f32x4 a, f32x4 b) {
  i32x4 r;
  r.x = cvtpk(a.x, a.y); r.y = cvtpk(a.z, a.w);
  r.z = cvtpk(b.x, b.y); r.w = cvtpk(b.z, b.w);
  return r;
}
__device__ __forceinline__ float waveRed(float v) {
#pragma unroll
  for (int o = 32; o > 0; o >>= 1) v += __shfl_down(v, o);
  return v;
}

#define MFMA(acc, A, B) \
  acc = __builtin_amdgcn_mfma_f32_16x16x32_bf16( \
      __builtin_bit_cast(bf16x8, A), __builtin_bit_cast(bf16x8, B), acc, 0, 0, 0)

// ------- fused: pack frag table (blocks 0..511) + sigma partials (512..767)
__global__ void lamp_packsig(const float* __restrict__ Bre, const float* __restrict__ Bim,
                             const float* __restrict__ Are, const float* __restrict__ Aim,
                             const float* __restrict__ zr, const float* __restrict__ zi,
                             unsigned short* __restrict__ fr, float* __restrict__ part)
{
  if (blockIdx.x < 512) {
    int i = blockIdx.x * 256 + threadIdx.x;     // 512*256 = 131072 = 16*8192
    int jj = i & 7, l = (i >> 3) & 63;
    int j = (i >> 9) & 15;                      // slot within chunk (0..15)
    int p = i >> 13;                            // chunk (0..15)
    float v = 0.f;
    if (j < 8) {
      int nt = 2*p + (j >> 2);
      int mat = (j >> 1) & 1;
      int ks = j & 1;
      int k = ks*32 + (l >> 4)*8 + jj;
      int n = nt*16 + (l & 15);
      v = (k < KK) ? (mat ? Bim[n*KK + k] : Bre[n*KK + k]) : 0.f;
    } else if (j < 14) {
      int jp = j - 8;
      int ct = jp >> 1, m = jp & 1;
      int k = p*32 + (l >> 4)*8 + jj;
      int c = ct*16 + (l & 15);
      v = m ? Aim[k*KK + c] : Are[k*KK + c];
    }
    fr[i] = f2bf(v);
  } else {
    const int bid = blockIdx.x - 512;           // 256 sigma blocks
    const int n4 = BATCH_*KK/4;
    const f32x4* a = (const f32x4*)zr; const f32x4* b = (const f32x4*)zi;
    float s = 0.f;
    for (int i = bid*256 + threadIdx.x; i < n4; i += 256*256) {
      f32x4 x = a[i]; s += x.x*x.x + x.y*x.y + x.z*x.z + x.w*x.w;
      f32x4 y = b[i]; s += y.x*y.x + y.y*y.y + y.z*y.z + y.w*y.w;
    }
    __shared__ float red[4];
    s = waveRed(s);
    int wave = threadIdx.x >> 6, lane = threadIdx.x & 63;
    if (lane == 0) red[wave] = s;
    __syncthreads();
    if (threadIdx.x == 0) part[bid] = red[0]+red[1]+red[2]+red[3];
  }
}

__global__ void lamp_sigfin(const float* __restrict__ part, float* __restrict__ sig)
{
  float s = part[threadIdx.x];   // 256 partials
  __shared__ float red[4];
  s = waveRed(s);
  int wave = threadIdx.x >> 6, lane = threadIdx.x & 63;
  if (lane == 0) red[wave] = s;
  __syncthreads();
  if (threadIdx.x == 0) sig[0] = sqrtf(red[0]+red[1]+red[2]+red[3]) / sqrtf((float)KK);
}

// ---------------- main fused kernel (R15) ----------------------------------
// Occupancy test: depth-1 double-buffer (fb[2] = 32 KB) + launch_bounds
// (256,4) -> 4 blocks/CU x 4 waves = 16 waves/CU (VGPR 64x4 = full pool,
// LDS 128 KB <= 160 KB). R13 (depth-2, 48 KB) was LDS-capped at 12 waves/CU.
// Trades depth-2's stage distance (~4.5 us, R12 vs R9) for +33% resident
// waves. 4-wave blocks restored (R14's 8-wave barrier convoying regressed).
// vmcnt ledger per iter [4 H][4 stage][4 stores]: steady vmcnt(4) retires
// stage(t+1), leaves this iter's stores in flight.
__global__ __launch_bounds__(256, 4) void lamp_main(
    const float* __restrict__ zre, const float* __restrict__ zim,
    const float* __restrict__ Hre, const float* __restrict__ Him,
    const unsigned short* __restrict__ fr,
    const float* __restrict__ sigp, const float* __restrict__ theta,
    float* __restrict__ out, float* __restrict__ bpart)
{
  __shared__ __align__(16) i32x4 fb[2][1024];   // 2 x 16384 B = 32 KB

  const int tid = threadIdx.x;
  const int wave = tid >> 6, lane = tid & 63;
  const int l15 = lane & 15, lg = lane >> 4;
  const int rbase = blockIdx.x * 64 + wave * 16;
  const int myrow = rbase + l15;
  const int phase = blockIdx.x & 15;
  const char* frc = (const char*)fr;

  // 256 threads x 4 x 16B = 16384 B per chunk
#define STAGE(bi, pp) do { \
    const char* gsrc_ = frc + (size_t)(pp)*16384 + wave*4096 + lane*16; \
    char* ldst_ = ((char*)&fb[bi][0]) + wave*4096 + lane*16; \
    _Pragma("unroll") \
    for (int s_ = 0; s_ < 4; ++s_) \
      __builtin_amdgcn_global_load_lds( \
          (const __attribute__((address_space(1))) void*)(gsrc_ + s_*1024), \
          (__attribute__((address_space(3))) void*)(ldst_ + s_*1024), 16, 0, 0); \
    asm volatile("" ::: "memory"); \
  } while (0)

  const float t0 = theta[0], t1 = theta[1], t2 = theta[2];
  const float sigma = sigp[0];
  const float s2 = (t0 * sigma) * (t0 * sigma);
  const float inv_s2 = 1.0f / s2;
  const float nhalf_inv_s2 = -0.5f * inv_s2;

  // z fragments (B operand of GEMM1'), K padded 48->64
  i32x4 zr[2], zi[2];
  {
    const float* pr = zre + (size_t)myrow * KK;
    const float* pi = zim + (size_t)myrow * KK;
#pragma unroll
    for (int ks = 0; ks < 2; ++ks) {
      const int k0 = ks*32 + lg*8;
      f32x4 a0 = {0,0,0,0}, a1 = {0,0,0,0}, b0 = {0,0,0,0}, b1 = {0,0,0,0};
      if (k0 < KK) {
        a0 = *(const f32x4*)(pr + k0); a1 = *(const f32x4*)(pr + k0 + 4);
        b0 = *(const f32x4*)(pi + k0); b1 = *(const f32x4*)(pi + k0 + 4);
      }
      zr[ks] = pack8bf_pk(a0, a1);
      zi[ks] = pack8bf_pk(b0, b1);
    }
  }

  const float* hrB = Hre + (size_t)myrow * NN + lg*4;
  const float* hiB = Him + (size_t)myrow * NN + lg*4;
  float* oRB = out + OFF_HHRE + (size_t)myrow * NN + lg*4;
  float* oIB = out + OFF_HHIM + (size_t)myrow * NN + lg*4;

  f32x4 ahR[3], ahI[3];
#pragma unroll
  for (int c = 0; c < 3; ++c) { ahR[c] = (f32x4){0,0,0,0}; ahI[c] = (f32x4){0,0,0,0}; }

  float dsr = 0.f, dsi = 0.f;
  const bool hi2 = (lg >= 2);
  const int srcA = l15 + ((lane & 16) << 1);
  const int srcB = srcA + 16;

  // prologue: stage chunk 0, full drain once
  STAGE(0, phase);
  asm volatile("s_waitcnt vmcnt(0)" ::: "memory");
  __builtin_amdgcn_s_barrier();

#pragma unroll 1
  for (int t = 0; t < 16; ++t) {
    const int cur = t & 1;
    const int p = (phase + t) & 15;

    // H loads first (deepest latency)
    f32x4 hR0 = *(const f32x4*)(hrB + 32*p);
    f32x4 hR1 = *(const f32x4*)(hrB + 32*p + 16);
    f32x4 hI0 = *(const f32x4*)(hiB + 32*p);
    f32x4 hI1 = *(const f32x4*)(hiB + 32*p + 16);

    // depth-1 stage: chunk t+1 into the other buffer
    if (t < 15) STAGE(cur ^ 1, (phase + t + 1) & 15);

    const i32x4* fbc = &fb[cur][0];
    i32x4 nzi0 = zi[0] ^ 0x80008000, nzi1 = zi[1] ^ 0x80008000;

    // ---- GEMM1' tiles (frags from LDS buffer cur) ----
    f32x4 aR0 = (f32x4){0,0,0,0}, aI0 = (f32x4){0,0,0,0};
    f32x4 aR1 = (f32x4){0,0,0,0}, aI1 = (f32x4){0,0,0,0};
    {
      i32x4 b0 = fbc[0*64 + lane];
      i32x4 b1 = fbc[1*64 + lane];
      i32x4 c0 = fbc[2*64 + lane];
      i32x4 c1 = fbc[3*64 + lane];
      i32x4 d0 = fbc[4*64 + lane];
      i32x4 d1 = fbc[5*64 + lane];
      i32x4 e0 = fbc[6*64 + lane];
      i32x4 e1 = fbc[7*64 + lane];
      __builtin_amdgcn_s_setprio(1);
      MFMA(aR0, b0, zr[0]); MFMA(aR0, b1, zr[1]);
      MFMA(aR0, c0, nzi0);  MFMA(aR0, c1, nzi1);
      MFMA(aI0, b0, zi[0]); MFMA(aI0, b1, zi[1]);
      MFMA(aI0, c0, zr[0]); MFMA(aI0, c1, zr[1]);
      MFMA(aR1, d0, zr[0]); MFMA(aR1, d1, zr[1]);
      MFMA(aR1, e0, nzi0);  MFMA(aR1, e1, nzi1);
      MFMA(aI1, d0, zi[0]); MFMA(aI1, d1, zi[1]);
      MFMA(aI1, e0, zr[0]); MFMA(aI1, e1, zr[1]);
      __builtin_amdgcn_s_setprio(0);
    }

    // ---- fused elementwise: R = H + Z, shrink, deriv ----
    f32x4 re0 = aR0 + hR0, im0 = aI0 + hI0;
    f32x4 re1 = aR1 + hR1, im1 = aI1 + hI1;
    f32x4 hhr0, hhi0, hhr1, hhi1;
#pragma unroll
    for (int c = 0; c < 4; ++c) {
      float x;
      x = re0[c]; { float e = __expf(x*x*nhalf_inv_s2); float te = t2*e;
        hhr0[c] = t1*x + x*te; dsr += t1 + te*(1.f - x*x*inv_s2); }
      x = im0[c]; { float e = __expf(x*x*nhalf_inv_s2); float te = t2*e;
        hhi0[c] = t1*x + x*te; dsi += t1 + te*(1.f - x*x*inv_s2); }
      x = re1[c]; { float e = __expf(x*x*nhalf_inv_s2); float te = t2*e;
        hhr1[c] = t1*x + x*te; dsr += t1 + te*(1.f - x*x*inv_s2); }
      x = im1[c]; { float e = __expf(x*x*nhalf_inv_s2); float te = t2*e;
        hhi1[c] = t1*x + x*te; dsi += t1 + te*(1.f - x*x*inv_s2); }
    }

    // ---- 4-lane exchange: acc row-slices -> GEMM2' B-operand frags ----
    {
      f32x4 selR, selI;
#pragma unroll
      for (int c = 0; c < 4; ++c) {
        selR[c] = hi2 ? hhr1[c] : hhr0[c];
        selI[c] = hi2 ? hhi1[c] : hhi0[c];
      }
      f32x4 w0, w1, v0, v1;
#pragma unroll
      for (int c = 0; c < 4; ++c) {
        w0[c] = __shfl(selR[c], srcA, 64);
        w1[c] = __shfl(selR[c], srcB, 64);
        v0[c] = __shfl(selI[c], srcA, 64);
        v1[c] = __shfl(selI[c], srcB, 64);
      }
      i32x4 hhRf = pack8bf_pk(w0, w1);
      i32x4 hhIf = pack8bf_pk(v0, v1);

      __builtin_amdgcn_s_setprio(1);
#pragma unroll
      for (int ct = 0; ct < 3; ++ct) {
        i32x4 par = fbc[(8 + 2*ct)*64 + lane];
        i32x4 pai = fbc[(9 + 2*ct)*64 + lane];
        i32x4 nai = pai ^ 0x80008000;
        MFMA(ahR[ct], par, hhRf);
        MFMA(ahR[ct], nai, hhIf);
        MFMA(ahI[ct], pai, hhRf);
        MFMA(ahI[ct], par, hhIf);
      }
      __builtin_amdgcn_s_setprio(0);
    }

    // ---- Hh stores LAST in VMEM order ----
    asm volatile("" ::: "memory");
    *(f32x4*)(oRB + 32*p)      = hhr0;
    *(f32x4*)(oRB + 32*p + 16) = hhr1;
    *(f32x4*)(oIB + 32*p)      = hhi0;
    *(f32x4*)(oIB + 32*p + 16) = hhi1;

    // counted barrier: vmcnt(4) retires stage(t+1) (and older), leaves this
    // iter's 4 stores in flight.
    asm volatile("s_waitcnt vmcnt(4)" ::: "memory");
    __builtin_amdgcn_s_barrier();
    __builtin_amdgcn_sched_barrier(0);
  }

  // epilogue: h stored as per-lane f32x4 row slices
#pragma unroll
  for (int ct = 0; ct < 3; ++ct) {
    *(f32x4*)(out + (size_t)myrow*KK + ct*16 + lg*4) = ahR[ct];
    *(f32x4*)(out + (size_t)(BATCH_*KK) + (size_t)myrow*KK + ct*16 + lg*4) = ahI[ct];
  }

  float rr = waveRed(dsr), ri = waveRed(dsi);
  if (lane == 0) {
    const int w = blockIdx.x * 4 + wave;
    bpart[2*w]     = rr;
    bpart[2*w + 1] = ri;
  }
#undef STAGE
}

// ---------------- b reduce (4096 wave-partials) ----------------
__global__ void lamp_bred(const float* __restrict__ bpart, float* __restrict__ bval)
{
  float sr = 0.f, si = 0.f;
  for (int m = threadIdx.x; m < 4096; m += 256) { sr += bpart[2*m]; si += bpart[2*m + 1]; }
  __shared__ float red[8];
  sr = waveRed(sr); si = waveRed(si);
  int wave = threadIdx.x >> 6, lane = threadIdx.x & 63;
  if (lane == 0) { red[wave] = sr; red[4 + wave] = si; }
  __syncthreads();
  if (threadIdx.x == 0) {
    bval[0] = (red[0]+red[1]+red[2]+red[3]) / (float)KK;
    bval[1] = (red[4]+red[5]+red[6]+red[7]) / (float)KK;
  }
}

// ---------------- z_new (in-place over parked h) ----------------
__global__ void lamp_znew(const float* __restrict__ ur, const float* __restrict__ ui,
                          const float* __restrict__ zr, const float* __restrict__ zi,
                          const float* __restrict__ bval, float* __restrict__ out)
{
  const float br = bval[0], bi = bval[1];
  const int n4 = BATCH_*KK/4;
  const f32x4* u4r = (const f32x4*)ur; const f32x4* u4i = (const f32x4*)ui;
  const f32x4* z4r = (const f32x4*)zr; const f32x4* z4i = (const f32x4*)zi;
  f32x4* o4r = (f32x4*)out;
  f32x4* o4i = (f32x4*)(out + BATCH_*KK);
  for (int i = blockIdx.x*blockDim.x + threadIdx.x; i < n4; i += gridDim.x*blockDim.x) {
    f32x4 h = o4r[i];
    o4r[i] = u4r[i] - h + br * z4r[i];
    f32x4 h2 = o4i[i];
    o4i[i] = u4i[i] - h2 + bi * z4i[i];
  }
}

extern "C" void kernel_launch(void* const* d_in, const int* in_sizes, int n_in,
                              void* d_out, int out_size, void* d_ws, size_t ws_size,
                              hipStream_t stream)
{
  const float* ur  = (const float*)d_in[0];
  const float* ui  = (const float*)d_in[1];
  const float* zr  = (const float*)d_in[2];
  const float* zi  = (const float*)d_in[3];
  const float* Hr  = (const float*)d_in[4];
  const float* Hi  = (const float*)d_in[5];
  const float* Bre = (const float*)d_in[6];
  const float* Bim = (const float*)d_in[7];
  const float* Are = (const float*)d_in[8];
  const float* Aim = (const float*)d_in[9];
  const float* th  = (const float*)d_in[10];
  float* out = (float*)d_out;
  char* ws = (char*)d_ws;
  unsigned short* fr = (unsigned short*)(ws + WS_FR);
  float* sigp  = (float*)(ws + WS_SIGP);
  float* sigv  = (float*)(ws + WS_SIGMA);
  float* bpart = (float*)(ws + WS_BPART);
  float* bval  = (float*)(ws + WS_BVAL);

  hipLaunchKernelGGL(lamp_packsig, dim3(768),  dim3(256), 0, stream,
                     Bre, Bim, Are, Aim, zr, zi, fr, sigp);
  hipLaunchKernelGGL(lamp_sigfin,  dim3(1),    dim3(256), 0, stream, sigp, sigv);
  hipLaunchKernelGGL(lamp_main,    dim3(1024), dim3(256), 0, stream,
                     zr, zi, Hr, Hi, fr, sigv, th, out, bpart);
  hipLaunchKernelGGL(lamp_bred,    dim3(1),    dim3(256), 0, stream, bpart, bval);
  hipLaunchKernelGGL(lamp_znew,    dim3(1024), dim3(256), 0, stream, ur, ui, zr, zi, bval, out);
}

// Round 16
// 160.314 us; speedup vs baseline: 1.0917x; 1.0917x over previous
//
#include <hip/hip_runtime.h>
#include <math.h>

#define BATCH_ 65536
#define NN 512
#define KK 48
#define OFF_HHRE (2*BATCH_*KK)            // 6291456
#define OFF_HHIM (OFF_HHRE + BATCH_*NN)   // 39845888

typedef float f32x4 __attribute__((ext_vector_type(4)));
typedef int   i32x4 __attribute__((ext_vector_type(4)));
typedef short bf16x8 __attribute__((ext_vector_type(8)));

// ---- ws layout (byte offsets) ----
#define WS_FR    0u         // 16 chunks x 16384 B = 262144 B
#define WS_SIGP  262144u    // 256 f32
#define WS_SIGMA 263168u    // 1 f32
#define WS_BPART 264192u    // 4096*2 f32 = 32 KB
#define WS_BVAL  296960u    // 2 f32

__device__ __forceinline__ unsigned short f2bf(float x) {
  unsigned u = __builtin_bit_cast(unsigned, x);
  unsigned r = (u + 0x7fffu + ((u >> 16) & 1u)) >> 16;
  return (unsigned short)r;
}
// single-instruction packed f32->bf16 (RTNE, same as f2bf)
__device__ __forceinline__ int cvtpk(float lo, float hi) {
  int r;
  asm("v_cvt_pk_bf16_f32 %0, %1, %2" : "=v"(r) : "v"(lo), "v"(hi));
  return r;
}
__device__ __forceinline__ i32x4 pack8bf_pk(f32x4 a, f32x4 b) {
  i32x4 r;
  r.x = cvtpk(a.x, a.y); r.y = cvtpk(a.z, a.w);
  r.z = cvtpk(b.x, b.y); r.w = cvtpk(b.z, b.w);
  return r;
}
__device__ __forceinline__ float waveRed(float v) {
#pragma unroll
  for (int o = 32; o > 0; o >>= 1) v += __shfl_down(v, o);
  return v;
}

#define MFMA(acc, A, B) \
  acc = __builtin_amdgcn_mfma_f32_16x16x32_bf16( \
      __builtin_bit_cast(bf16x8, A), __builtin_bit_cast(bf16x8, B), acc, 0, 0, 0)

// ------- fused: pack frag table (blocks 0..511) + sigma partials (512..767)
__global__ void lamp_packsig(const float* __restrict__ Bre, const float* __restrict__ Bim,
                             const float* __restrict__ Are, const float* __restrict__ Aim,
                             const float* __restrict__ zr, const float* __restrict__ zi,
                             unsigned short* __restrict__ fr, float* __restrict__ part)
{
  if (blockIdx.x < 512) {
    int i = blockIdx.x * 256 + threadIdx.x;     // 512*256 = 131072 = 16*8192
    int jj = i & 7, l = (i >> 3) & 63;
    int j = (i >> 9) & 15;                      // slot within chunk (0..15)
    int p = i >> 13;                            // chunk (0..15)
    float v = 0.f;
    if (j < 8) {
      int nt = 2*p + (j >> 2);
      int mat = (j >> 1) & 1;
      int ks = j & 1;
      int k = ks*32 + (l >> 4)*8 + jj;
      int n = nt*16 + (l & 15);
      v = (k < KK) ? (mat ? Bim[n*KK + k] : Bre[n*KK + k]) : 0.f;
    } else if (j < 14) {
      int jp = j - 8;
      int ct = jp >> 1, m = jp & 1;
      int k = p*32 + (l >> 4)*8 + jj;
      int c = ct*16 + (l & 15);
      v = m ? Aim[k*KK + c] : Are[k*KK + c];
    }
    fr[i] = f2bf(v);
  } else {
    const int bid = blockIdx.x - 512;           // 256 sigma blocks
    const int n4 = BATCH_*KK/4;
    const f32x4* a = (const f32x4*)zr; const f32x4* b = (const f32x4*)zi;
    float s = 0.f;
    for (int i = bid*256 + threadIdx.x; i < n4; i += 256*256) {
      f32x4 x = a[i]; s += x.x*x.x + x.y*x.y + x.z*x.z + x.w*x.w;
      f32x4 y = b[i]; s += y.x*y.x + y.y*y.y + y.z*y.z + y.w*y.w;
    }
    __shared__ float red[4];
    s = waveRed(s);
    int wave = threadIdx.x >> 6, lane = threadIdx.x & 63;
    if (lane == 0) red[wave] = s;
    __syncthreads();
    if (threadIdx.x == 0) part[bid] = red[0]+red[1]+red[2]+red[3];
  }
}

__global__ void lamp_sigfin(const float* __restrict__ part, float* __restrict__ sig)
{
  float s = part[threadIdx.x];   // 256 partials
  __shared__ float red[4];
  s = waveRed(s);
  int wave = threadIdx.x >> 6, lane = threadIdx.x & 63;
  if (lane == 0) red[wave] = s;
  __syncthreads();
  if (threadIdx.x == 0) sig[0] = sqrtf(red[0]+red[1]+red[2]+red[3]) / sqrtf((float)KK);
}

// ---------------- main fused kernel (R16 = R13 verbatim) --------------------
// Best measured configuration (160.1 us total): depth-2 triple-buffered LDS
// staging (fb[3] = 48 KB, 3 blocks/CU = 12 waves/CU), counted vmcnt(8)
// barrier, cvt_pk, plain stores, setprio, VGPR<=64 via launch_bounds(256,4),
// 4-wave blocks. R14 (8-wave blocks) and R15 (depth-1 + 16 waves/CU) both
// regressed -> depth-2 stage distance dominates occupancy on this kernel.
__global__ __launch_bounds__(256, 4) void lamp_main(
    const float* __restrict__ zre, const float* __restrict__ zim,
    const float* __restrict__ Hre, const float* __restrict__ Him,
    const unsigned short* __restrict__ fr,
    const float* __restrict__ sigp, const float* __restrict__ theta,
    float* __restrict__ out, float* __restrict__ bpart)
{
  __shared__ __align__(16) i32x4 fb[3][1024];   // 3 x 16384 B = 48 KB

  const int tid = threadIdx.x;
  const int wave = tid >> 6, lane = tid & 63;
  const int l15 = lane & 15, lg = lane >> 4;
  const int rbase = blockIdx.x * 64 + wave * 16;
  const int myrow = rbase + l15;
  const int phase = blockIdx.x & 15;
  const char* frc = (const char*)fr;

#define STAGE(bi, pp) do { \
    const char* gsrc_ = frc + (size_t)(pp)*16384 + wave*4096 + lane*16; \
    char* ldst_ = ((char*)&fb[bi][0]) + wave*4096 + lane*16; \
    _Pragma("unroll") \
    for (int s_ = 0; s_ < 4; ++s_) \
      __builtin_amdgcn_global_load_lds( \
          (const __attribute__((address_space(1))) void*)(gsrc_ + s_*1024), \
          (__attribute__((address_space(3))) void*)(ldst_ + s_*1024), 16, 0, 0); \
    asm volatile("" ::: "memory"); \
  } while (0)

  const float t0 = theta[0], t1 = theta[1], t2 = theta[2];
  const float sigma = sigp[0];
  const float s2 = (t0 * sigma) * (t0 * sigma);
  const float inv_s2 = 1.0f / s2;
  const float nhalf_inv_s2 = -0.5f * inv_s2;

  // z fragments (B operand of GEMM1'), K padded 48->64
  i32x4 zr[2], zi[2];
  {
    const float* pr = zre + (size_t)myrow * KK;
    const float* pi = zim + (size_t)myrow * KK;
#pragma unroll
    for (int ks = 0; ks < 2; ++ks) {
      const int k0 = ks*32 + lg*8;
      f32x4 a0 = {0,0,0,0}, a1 = {0,0,0,0}, b0 = {0,0,0,0}, b1 = {0,0,0,0};
      if (k0 < KK) {
        a0 = *(const f32x4*)(pr + k0); a1 = *(const f32x4*)(pr + k0 + 4);
        b0 = *(const f32x4*)(pi + k0); b1 = *(const f32x4*)(pi + k0 + 4);
      }
      zr[ks] = pack8bf_pk(a0, a1);
      zi[ks] = pack8bf_pk(b0, b1);
    }
  }

  const float* hrB = Hre + (size_t)myrow * NN + lg*4;
  const float* hiB = Him + (size_t)myrow * NN + lg*4;
  float* oRB = out + OFF_HHRE + (size_t)myrow * NN + lg*4;
  float* oIB = out + OFF_HHIM + (size_t)myrow * NN + lg*4;

  f32x4 ahR[3], ahI[3];
#pragma unroll
  for (int c = 0; c < 3; ++c) { ahR[c] = (f32x4){0,0,0,0}; ahI[c] = (f32x4){0,0,0,0}; }

  float dsr = 0.f, dsi = 0.f;
  const bool hi2 = (lg >= 2);
  const int srcA = l15 + ((lane & 16) << 1);
  const int srcB = srcA + 16;

  // prologue: stage chunks 0 and 1 (depth-2 pipeline), full drain once
  STAGE(0, phase);
  STAGE(1, (phase + 1) & 15);
  asm volatile("s_waitcnt vmcnt(0)" ::: "memory");
  __builtin_amdgcn_s_barrier();

  // buffer index t%3 tracked incrementally (avoid runtime modulo)
  int cur = 0, nxt2 = 2;

#pragma unroll 1
  for (int t = 0; t < 16; ++t) {
    const int p = (phase + t) & 15;

    // H loads first (deepest latency)
    f32x4 hR0 = *(const f32x4*)(hrB + 32*p);
    f32x4 hR1 = *(const f32x4*)(hrB + 32*p + 16);
    f32x4 hI0 = *(const f32x4*)(hiB + 32*p);
    f32x4 hI1 = *(const f32x4*)(hiB + 32*p + 16);

    // depth-2 stage: chunk t+2 into buffer (t+2)%3
    if (t < 14) STAGE(nxt2, (phase + t + 2) & 15);

    const i32x4* fbc = &fb[cur][0];
    i32x4 nzi0 = zi[0] ^ 0x80008000, nzi1 = zi[1] ^ 0x80008000;

    // ---- GEMM1' tiles (frags from LDS buffer cur) ----
    f32x4 aR0 = (f32x4){0,0,0,0}, aI0 = (f32x4){0,0,0,0};
    f32x4 aR1 = (f32x4){0,0,0,0}, aI1 = (f32x4){0,0,0,0};
    {
      i32x4 b0 = fbc[0*64 + lane];
      i32x4 b1 = fbc[1*64 + lane];
      i32x4 c0 = fbc[2*64 + lane];
      i32x4 c1 = fbc[3*64 + lane];
      i32x4 d0 = fbc[4*64 + lane];
      i32x4 d1 = fbc[5*64 + lane];
      i32x4 e0 = fbc[6*64 + lane];
      i32x4 e1 = fbc[7*64 + lane];
      __builtin_amdgcn_s_setprio(1);
      MFMA(aR0, b0, zr[0]); MFMA(aR0, b1, zr[1]);
      MFMA(aR0, c0, nzi0);  MFMA(aR0, c1, nzi1);
      MFMA(aI0, b0, zi[0]); MFMA(aI0, b1, zi[1]);
      MFMA(aI0, c0, zr[0]); MFMA(aI0, c1, zr[1]);
      MFMA(aR1, d0, zr[0]); MFMA(aR1, d1, zr[1]);
      MFMA(aR1, e0, nzi0);  MFMA(aR1, e1, nzi1);
      MFMA(aI1, d0, zi[0]); MFMA(aI1, d1, zi[1]);
      MFMA(aI1, e0, zr[0]); MFMA(aI1, e1, zr[1]);
      __builtin_amdgcn_s_setprio(0);
    }

    // ---- fused elementwise: R = H + Z, shrink, deriv ----
    f32x4 re0 = aR0 + hR0, im0 = aI0 + hI0;
    f32x4 re1 = aR1 + hR1, im1 = aI1 + hI1;
    f32x4 hhr0, hhi0, hhr1, hhi1;
#pragma unroll
    for (int c = 0; c < 4; ++c) {
      float x;
      x = re0[c]; { float e = __expf(x*x*nhalf_inv_s2); float te = t2*e;
        hhr0[c] = t1*x + x*te; dsr += t1 + te*(1.f - x*x*inv_s2); }
      x = im0[c]; { float e = __expf(x*x*nhalf_inv_s2); float te = t2*e;
        hhi0[c] = t1*x + x*te; dsi += t1 + te*(1.f - x*x*inv_s2); }
      x = re1[c]; { float e = __expf(x*x*nhalf_inv_s2); float te = t2*e;
        hhr1[c] = t1*x + x*te; dsr += t1 + te*(1.f - x*x*inv_s2); }
      x = im1[c]; { float e = __expf(x*x*nhalf_inv_s2); float te = t2*e;
        hhi1[c] = t1*x + x*te; dsi += t1 + te*(1.f - x*x*inv_s2); }
    }

    // ---- 4-lane exchange: acc row-slices -> GEMM2' B-operand frags ----
    {
      f32x4 selR, selI;
#pragma unroll
      for (int c = 0; c < 4; ++c) {
        selR[c] = hi2 ? hhr1[c] : hhr0[c];
        selI[c] = hi2 ? hhi1[c] : hhi0[c];
      }
      f32x4 w0, w1, v0, v1;
#pragma unroll
      for (int c = 0; c < 4; ++c) {
        w0[c] = __shfl(selR[c], srcA, 64);
        w1[c] = __shfl(selR[c], srcB, 64);
        v0[c] = __shfl(selI[c], srcA, 64);
        v1[c] = __shfl(selI[c], srcB, 64);
      }
      i32x4 hhRf = pack8bf_pk(w0, w1);
      i32x4 hhIf = pack8bf_pk(v0, v1);

      __builtin_amdgcn_s_setprio(1);
#pragma unroll
      for (int ct = 0; ct < 3; ++ct) {
        i32x4 par = fbc[(8 + 2*ct)*64 + lane];
        i32x4 pai = fbc[(9 + 2*ct)*64 + lane];
        i32x4 nai = pai ^ 0x80008000;
        MFMA(ahR[ct], par, hhRf);
        MFMA(ahR[ct], nai, hhIf);
        MFMA(ahI[ct], pai, hhRf);
        MFMA(ahI[ct], par, hhIf);
      }
      __builtin_amdgcn_s_setprio(0);
    }

    // ---- Hh stores LAST in VMEM order ----
    asm volatile("" ::: "memory");
    *(f32x4*)(oRB + 32*p)      = hhr0;
    *(f32x4*)(oRB + 32*p + 16) = hhr1;
    *(f32x4*)(oIB + 32*p)      = hhi0;
    *(f32x4*)(oIB + 32*p + 16) = hhi1;

    // counted barrier: steady state vmcnt(8) keeps {stage(t+2), stores(t)}
    // in flight, retires stage(t+1) and older. Tail: vmcnt(4).
    if (t < 14) {
      asm volatile("s_waitcnt vmcnt(8)" ::: "memory");
    } else {
      asm volatile("s_waitcnt vmcnt(4)" ::: "memory");
    }
    __builtin_amdgcn_s_barrier();
    __builtin_amdgcn_sched_barrier(0);

    cur = (cur == 2) ? 0 : cur + 1;
    nxt2 = (nxt2 == 2) ? 0 : nxt2 + 1;
  }

  // epilogue: h stored as per-lane f32x4 row slices
#pragma unroll
  for (int ct = 0; ct < 3; ++ct) {
    *(f32x4*)(out + (size_t)myrow*KK + ct*16 + lg*4) = ahR[ct];
    *(f32x4*)(out + (size_t)(BATCH_*KK) + (size_t)myrow*KK + ct*16 + lg*4) = ahI[ct];
  }

  float rr = waveRed(dsr), ri = waveRed(dsi);
  if (lane == 0) {
    const int w = blockIdx.x * 4 + wave;
    bpart[2*w]     = rr;
    bpart[2*w + 1] = ri;
  }
#undef STAGE
}

// ---------------- b reduce (4096 wave-partials) ----------------
__global__ void lamp_bred(const float* __restrict__ bpart, float* __restrict__ bval)
{
  float sr = 0.f, si = 0.f;
  for (int m = threadIdx.x; m < 4096; m += 256) { sr += bpart[2*m]; si += bpart[2*m + 1]; }
  __shared__ float red[8];
  sr = waveRed(sr); si = waveRed(si);
  int wave = threadIdx.x >> 6, lane = threadIdx.x & 63;
  if (lane == 0) { red[wave] = sr; red[4 + wave] = si; }
  __syncthreads();
  if (threadIdx.x == 0) {
    bval[0] = (red[0]+red[1]+red[2]+red[3]) / (float)KK;
    bval[1] = (red[4]+red[5]+red[6]+red[7]) / (float)KK;
  }
}

// ---------------- z_new (in-place over parked h) ----------------
__global__ void lamp_znew(const float* __restrict__ ur, const float* __restrict__ ui,
                          const float* __restrict__ zr, const float* __restrict__ zi,
                          const float* __restrict__ bval, float* __restrict__ out)
{
  const float br = bval[0], bi = bval[1];
  const int n4 = BATCH_*KK/4;
  const f32x4* u4r = (const f32x4*)ur; const f32x4* u4i = (const f32x4*)ui;
  const f32x4* z4r = (const f32x4*)zr; const f32x4* z4i = (const f32x4*)zi;
  f32x4* o4r = (f32x4*)out;
  f32x4* o4i = (f32x4*)(out + BATCH_*KK);
  for (int i = blockIdx.x*blockDim.x + threadIdx.x; i < n4; i += gridDim.x*blockDim.x) {
    f32x4 h = o4r[i];
    o4r[i] = u4r[i] - h + br * z4r[i];
    f32x4 h2 = o4i[i];
    o4i[i] = u4i[i] - h2 + bi * z4i[i];
  }
}

extern "C" void kernel_launch(void* const* d_in, const int* in_sizes, int n_in,
                              void* d_out, int out_size, void* d_ws, size_t ws_size,
                              hipStream_t stream)
{
  const float* ur  = (const float*)d_in[0];
  const float* ui  = (const float*)d_in[1];
  const float* zr  = (const float*)d_in[2];
  const float* zi  = (const float*)d_in[3];
  const float* Hr  = (const float*)d_in[4];
  const float* Hi  = (const float*)d_in[5];
  const float* Bre = (const float*)d_in[6];
  const float* Bim = (const float*)d_in[7];
  const float* Are = (const float*)d_in[8];
  const float* Aim = (const float*)d_in[9];
  const float* th  = (const float*)d_in[10];
  float* out = (float*)d_out;
  char* ws = (char*)d_ws;
  unsigned short* fr = (unsigned short*)(ws + WS_FR);
  float* sigp  = (float*)(ws + WS_SIGP);
  float* sigv  = (float*)(ws + WS_SIGMA);
  float* bpart = (float*)(ws + WS_BPART);
  float* bval  = (float*)(ws + WS_BVAL);

  hipLaunchKernelGGL(lamp_packsig, dim3(768),  dim3(256), 0, stream,
                     Bre, Bim, Are, Aim, zr, zi, fr, sigp);
  hipLaunchKernelGGL(lamp_sigfin,  dim3(1),    dim3(256), 0, stream, sigp, sigv);
  hipLaunchKernelGGL(lamp_main,    dim3(1024), dim3(256), 0, stream,
                     zr, zi, Hr, Hi, fr, sigv, th, out, bpart);
  hipLaunchKernelGGL(lamp_bred,    dim3(1),    dim3(256), 0, stream, bpart, bval);
  hipLaunchKernelGGL(lamp_znew,    dim3(1024), dim3(256), 0, stream, ur, ui, zr, zi, bval, out);
}